// Round 24
// baseline (47.791 us; speedup 1.0000x reference)
//
#include <hip/hip_runtime.h>

#define BSES 64
#define EDIM 128
#define HDIM 128
#define NT 40   // targets per block: 500 blocks = 1.95/CU (balanced grid)
#define TPB 640 // 10 waves/block -> 5 waves/SIMD at 2 blocks/CU
#define KSCALE 2.8853900817779268f  // 2*log2(e): exp(2x) = exp2(KSCALE*x)

typedef float v2f __attribute__((ext_vector_type(2)));

__device__ __forceinline__ float fexp2(float x) {
#if __has_builtin(__builtin_amdgcn_exp2f)
  return __builtin_amdgcn_exp2f(x);
#else
  return exp2f(x);
#endif
}
__device__ __forceinline__ float frcp(float x) {
#if __has_builtin(__builtin_amdgcn_rcpf)
  return __builtin_amdgcn_rcpf(x);
#else
  return 1.0f / x;
#endif
}
__device__ __forceinline__ v2f mkv2(float a, float b) {
  v2f r;
  r.x = a;
  r.y = b;
  return r;
}

// 8-term batched reciprocal sum via PACKED f32 (R20/R22/R23-proven).
__device__ __forceinline__ float g4pk8(float4 s0, float4 s1, float4 w0,
                                       float4 w1, float4 v0, float4 v1,
                                       float acc) {
  const v2f one = {1.f, 1.f};
  v2f s01 = mkv2(s0.x, s0.y), s23 = mkv2(s0.z, s0.w);
  v2f s45 = mkv2(s1.x, s1.y), s67 = mkv2(s1.z, s1.w);
  v2f w01 = mkv2(w0.x, w0.y), w23 = mkv2(w0.z, w0.w);
  v2f w45 = mkv2(w1.x, w1.y), w67 = mkv2(w1.z, w1.w);
  v2f v01 = mkv2(v0.x, v0.y), v23 = mkv2(v0.z, v0.w);
  v2f v45 = mkv2(v1.x, v1.y), v67 = mkv2(v1.z, v1.w);
  v2f x01 = __builtin_elementwise_fma(s01, v01, one);
  v2f x23 = __builtin_elementwise_fma(s23, v23, one);
  v2f x45 = __builtin_elementwise_fma(s45, v45, one);
  v2f x67 = __builtin_elementwise_fma(s67, v67, one);
  v2f p03 = x01 * x23;
  v2f p47 = x45 * x67;
  v2f n03 = __builtin_elementwise_fma(w23, x01, w01 * x23);
  v2f n47 = __builtin_elementwise_fma(w67, x45, w45 * x67);
  v2f num = __builtin_elementwise_fma(n47, p03, n03 * p47);
  v2f den = p03 * p47;
  acc = fmaf(num.x, frcp(den.x), acc);
  acc = fmaf(num.y, frcp(den.y), acc);
  return acc;
}

// Session projection (proven, verbatim). esp4 PACKED [h/4][b][4]; plus C.
__global__ __launch_bounds__(256) void taa_esp(
    const float* __restrict__ sess, const float* __restrict__ W1,
    const float* __restrict__ b1, const float* __restrict__ W3,
    const float* __restrict__ b3, float* __restrict__ esp4,
    float* __restrict__ C_out) {
  int t = blockIdx.x * 256 + threadIdx.x;
  if (t < BSES * HDIM) {
    int b = t >> 7, h = t & 127;
    const float* srow = sess + b * EDIM;
    float acc = 0.f;
#pragma unroll 4
    for (int e = 0; e < EDIM; ++e)
      acc = fmaf(srow[e], W1[e * HDIM + h], acc);
    esp4[(h >> 2) * 256 + b * 4 + (h & 3)] = fexp2((acc + b1[h]) * KSCALE);
  }
  if (t == 0) {
    float s = b3[0];
    for (int i = 0; i < HDIM; ++i) s += W3[i];
    *C_out = s;
  }
}

// Score 2 targets (rows t0, t0+1) x TWO sessions (2*sp2, 2*sp2+1).
// Same per-CU LDS-pipe load as R23 (2-session amortization preserved);
// per-thread chains are 2.5x shorter -> latency hides under 5 waves/SIMD.
__device__ __forceinline__ void score2x2(
    const float* __restrict__ et, int t0, int sp2,
    const float* __restrict__ esp4, const float* __restrict__ w3,
    float accA[2], float accB[2]) {
  const float* base = et + t0 * HDIM;
#pragma unroll 2
  for (int c = 0; c < 8; ++c) {
    float4 spA[4], spB[4];
#pragma unroll
    for (int k = 0; k < 4; ++k) {
      const float* p = esp4 + ((c << 2) + k) * 256 + (sp2 << 3);
      spA[k] = *(const float4*)p;        // session 2*sp2
      spB[k] = *(const float4*)(p + 4);  // session 2*sp2+1
    }
    float4 wq[4];
#pragma unroll
    for (int k = 0; k < 4; ++k)
      wq[k] = *(const float4*)(w3 + (c << 4) + k * 4);  // uniform
#pragma unroll
    for (int t = 0; t < 2; ++t) {
      const float* rp = base + t * HDIM + (c << 4);
      float4 v0 = *(const float4*)(rp + 0);  // 2-addr ds_read broadcast
      float4 v1 = *(const float4*)(rp + 4);
      float4 v2 = *(const float4*)(rp + 8);
      float4 v3 = *(const float4*)(rp + 12);
      accA[t] = g4pk8(spA[0], spA[1], wq[0], wq[1], v0, v1, accA[t]);
      accA[t] = g4pk8(spA[2], spA[3], wq[2], wq[3], v2, v3, accA[t]);
      accB[t] = g4pk8(spB[0], spB[1], wq[0], wq[1], v0, v1, accB[t]);
      accB[t] = g4pk8(spB[2], spB[3], wq[2], wq[3], v2, v3, accB[t]);
    }
  }
}

// Fused per 40-target tile, 640 threads (10 waves). Same structure and
// per-block traffic as R23; only the work partition changed for TLP:
// P2 thread = 2 rows x 4 h; P3 thread = 2 sessions x 2 targets.
// score[b][n] = C - 2 * sum_h w3[h] * rcp(fma(esp[b][h], etp[n][h], 1))
__global__ __launch_bounds__(TPB) void taa_fused(
    const float* __restrict__ emb, const float* __restrict__ W2,
    const float* __restrict__ b2, const float* __restrict__ esp4,
    const float* __restrict__ w3, const float* __restrict__ Cptr,
    float* __restrict__ out, int N) {
  __shared__ float sm[NT][132];       // emb tile, padded stride
  __shared__ float et[NT * HDIM];     // exp2(tp') tile
  const int nb = blockIdx.x * NT;
  const int tid = threadIdx.x;

  // Phase 1: stage emb tile (coalesced float4, 2 per thread).
  for (int k = tid; k < NT * 32; k += TPB) {
    int r = k >> 5, c4 = k & 31;
    float4 v = make_float4(0.f, 0.f, 0.f, 0.f);
    if (nb + r < N) v = ((const float4*)(emb + (size_t)(nb + r) * EDIM))[c4];
    *(float4*)&sm[r][c4 * 4] = v;
  }
  __syncthreads();

  // Phase 2: GEMM + exp2 -> et (LDS). Thread = 2 rows x 4 h.
  {
    const int h4 = (tid & 31) * 4;
    const int rg = tid >> 5;  // 0..19 -> rows rg*2, rg*2+1
    float acc[2][4];
#pragma unroll
    for (int j = 0; j < 2; ++j)
#pragma unroll
      for (int q = 0; q < 4; ++q) acc[j][q] = 0.f;
    for (int e = 0; e < EDIM; e += 4) {
      float4 w[4];
#pragma unroll
      for (int q = 0; q < 4; ++q)
        w[q] = *(const float4*)(W2 + (size_t)(e + q) * HDIM + h4);
#pragma unroll
      for (int j = 0; j < 2; ++j) {
        float4 em = *(const float4*)&sm[rg * 2 + j][e];
        acc[j][0] = fmaf(em.x, w[0].x, acc[j][0]);
        acc[j][1] = fmaf(em.x, w[0].y, acc[j][1]);
        acc[j][2] = fmaf(em.x, w[0].z, acc[j][2]);
        acc[j][3] = fmaf(em.x, w[0].w, acc[j][3]);
        acc[j][0] = fmaf(em.y, w[1].x, acc[j][0]);
        acc[j][1] = fmaf(em.y, w[1].y, acc[j][1]);
        acc[j][2] = fmaf(em.y, w[1].z, acc[j][2]);
        acc[j][3] = fmaf(em.y, w[1].w, acc[j][3]);
        acc[j][0] = fmaf(em.z, w[2].x, acc[j][0]);
        acc[j][1] = fmaf(em.z, w[2].y, acc[j][1]);
        acc[j][2] = fmaf(em.z, w[2].z, acc[j][2]);
        acc[j][3] = fmaf(em.z, w[2].w, acc[j][3]);
        acc[j][0] = fmaf(em.w, w[3].x, acc[j][0]);
        acc[j][1] = fmaf(em.w, w[3].y, acc[j][1]);
        acc[j][2] = fmaf(em.w, w[3].z, acc[j][2]);
        acc[j][3] = fmaf(em.w, w[3].w, acc[j][3]);
      }
    }
    float4 bb2 = *(const float4*)(b2 + h4);
#pragma unroll
    for (int j = 0; j < 2; ++j) {
      int nr = rg * 2 + j;
      float4 o;
      o.x = fexp2((acc[j][0] + bb2.x) * KSCALE);
      o.y = fexp2((acc[j][1] + bb2.y) * KSCALE);
      o.z = fexp2((acc[j][2] + bb2.z) * KSCALE);
      o.w = fexp2((acc[j][3] + bb2.w) * KSCALE);
      *(float4*)&et[nr * HDIM + h4] = o;  // wave-contiguous, conflict-free
    }
  }
  __syncthreads();

  // Phase 3: scoring. lane&31 = session-pair; (wave*2 + lane>>5) -> 2-target
  // group. Thread = 2 sessions x 2 targets.
  const int lane = tid & 63;
  const int wv = tid >> 6;          // 0..9
  const int sp2 = lane & 31;        // sessions 2*sp2, 2*sp2+1
  const int th = lane >> 5;
  const int t0 = (wv * 2 + th) * 2; // 0,2,...,38
  float accA[2] = {0.f, 0.f};
  float accB[2] = {0.f, 0.f};
  score2x2(et, t0, sp2, esp4, w3, accA, accB);

  const float Cv = *Cptr;  // uniform
  const int n0 = nb + t0;
  const int sA = sp2 * 2, sB = sA + 1;
  float* poA = out + (size_t)sA * N + n0;
  float* poB = out + (size_t)sB * N + n0;
  if (n0 + 1 < N) {
    float2 rA, rB;
    rA.x = fmaf(-2.f, accA[0], Cv);
    rA.y = fmaf(-2.f, accA[1], Cv);
    rB.x = fmaf(-2.f, accB[0], Cv);
    rB.y = fmaf(-2.f, accB[1], Cv);
    *(float2*)poA = rA;
    *(float2*)poB = rB;
  } else if (n0 < N) {
    poA[0] = fmaf(-2.f, accA[0], Cv);
    poB[0] = fmaf(-2.f, accB[0], Cv);
  }
}

extern "C" void kernel_launch(void* const* d_in, const int* in_sizes, int n_in,
                              void* d_out, int out_size, void* d_ws, size_t ws_size,
                              hipStream_t stream) {
  const float* sess = (const float*)d_in[0];
  const float* emb  = (const float*)d_in[1];
  const float* W1   = (const float*)d_in[2];
  const float* b1   = (const float*)d_in[3];
  const float* W2   = (const float*)d_in[4];
  const float* b2   = (const float*)d_in[5];
  const float* W3   = (const float*)d_in[6];
  const float* b3   = (const float*)d_in[7];
  float* out = (float*)d_out;
  const int B = in_sizes[0] / EDIM;   // 64
  const int N = in_sizes[1] / EDIM;   // 20000

  float* esp4 = (float*)d_ws;                     // B*128 floats (packed)
  float* Cp   = esp4 + (size_t)BSES * HDIM;       // 1 float

  taa_esp<<<(B * HDIM + 255) / 256, 256, 0, stream>>>(sess, W1, b1, W3, b3,
                                                      esp4, Cp);
  taa_fused<<<(N + NT - 1) / NT, TPB, 0, stream>>>(emb, W2, b2, esp4, W3, Cp,
                                                   out, N);
}

// Round 25
// 39.411 us; speedup vs baseline: 1.2126x; 1.2126x over previous
//
#include <hip/hip_runtime.h>

#define BSES 64
#define EDIM 128
#define HDIM 128
#define NT 40  // targets per block: 500 blocks = 1.95/CU (balanced grid)
#define KSCALE 2.8853900817779268f  // 2*log2(e): exp(2x) = exp2(KSCALE*x)

typedef float v2f __attribute__((ext_vector_type(2)));

__device__ __forceinline__ float fexp2(float x) {
#if __has_builtin(__builtin_amdgcn_exp2f)
  return __builtin_amdgcn_exp2f(x);
#else
  return exp2f(x);
#endif
}
__device__ __forceinline__ float frcp(float x) {
#if __has_builtin(__builtin_amdgcn_rcpf)
  return __builtin_amdgcn_rcpf(x);
#else
  return 1.0f / x;
#endif
}
__device__ __forceinline__ v2f mkv2(float a, float b) {
  v2f r;
  r.x = a;
  r.y = b;
  return r;
}

// 8-term batched reciprocal sum via PACKED f32 (R20/R22/R23-proven).
__device__ __forceinline__ float g4pk8(float4 s0, float4 s1, float4 w0,
                                       float4 w1, float4 v0, float4 v1,
                                       float acc) {
  const v2f one = {1.f, 1.f};
  v2f s01 = mkv2(s0.x, s0.y), s23 = mkv2(s0.z, s0.w);
  v2f s45 = mkv2(s1.x, s1.y), s67 = mkv2(s1.z, s1.w);
  v2f w01 = mkv2(w0.x, w0.y), w23 = mkv2(w0.z, w0.w);
  v2f w45 = mkv2(w1.x, w1.y), w67 = mkv2(w1.z, w1.w);
  v2f v01 = mkv2(v0.x, v0.y), v23 = mkv2(v0.z, v0.w);
  v2f v45 = mkv2(v1.x, v1.y), v67 = mkv2(v1.z, v1.w);
  v2f x01 = __builtin_elementwise_fma(s01, v01, one);
  v2f x23 = __builtin_elementwise_fma(s23, v23, one);
  v2f x45 = __builtin_elementwise_fma(s45, v45, one);
  v2f x67 = __builtin_elementwise_fma(s67, v67, one);
  v2f p03 = x01 * x23;
  v2f p47 = x45 * x67;
  v2f n03 = __builtin_elementwise_fma(w23, x01, w01 * x23);
  v2f n47 = __builtin_elementwise_fma(w67, x45, w45 * x67);
  v2f num = __builtin_elementwise_fma(n47, p03, n03 * p47);
  v2f den = p03 * p47;
  acc = fmaf(num.x, frcp(den.x), acc);
  acc = fmaf(num.y, frcp(den.y), acc);
  return acc;
}

// Session projection (proven, verbatim). esp4 PACKED [h/4][b][4]; plus C.
__global__ __launch_bounds__(256) void taa_esp(
    const float* __restrict__ sess, const float* __restrict__ W1,
    const float* __restrict__ b1, const float* __restrict__ W3,
    const float* __restrict__ b3, float* __restrict__ esp4,
    float* __restrict__ C_out) {
  int t = blockIdx.x * 256 + threadIdx.x;
  if (t < BSES * HDIM) {
    int b = t >> 7, h = t & 127;
    const float* srow = sess + b * EDIM;
    float acc = 0.f;
#pragma unroll 4
    for (int e = 0; e < EDIM; ++e)
      acc = fmaf(srow[e], W1[e * HDIM + h], acc);
    esp4[(h >> 2) * 256 + b * 4 + (h & 3)] = fexp2((acc + b1[h]) * KSCALE);
  }
  if (t == 0) {
    float s = b3[0];
    for (int i = 0; i < HDIM; ++i) s += W3[i];
    *C_out = s;
  }
}

// Score 5 targets (rows t0..t0+4) x TWO sessions (R23-proven), with a
// per-wave c-loop SKEW (cstart) so co-resident waves hit different pipes
// (LDS / VMEM / VALU) at any instant instead of convoying at barriers.
// The c-sum is order-independent -> same result.
__device__ __forceinline__ void score5x2(
    const float* __restrict__ et, int t0, int sp2,
    const float* __restrict__ esp4, const float* __restrict__ w3,
    float accA[5], float accB[5], int cstart) {
  const float* base = et + t0 * HDIM;
#pragma unroll 2
  for (int ci = 0; ci < 8; ++ci) {
    const int c = (ci + cstart) & 7;
    float4 spA[4], spB[4];
#pragma unroll
    for (int k = 0; k < 4; ++k) {
      const float* p = esp4 + ((c << 2) + k) * 256 + (sp2 << 3);
      spA[k] = *(const float4*)p;        // session 2*sp2
      spB[k] = *(const float4*)(p + 4);  // session 2*sp2+1
    }
    float4 wq[4];
#pragma unroll
    for (int k = 0; k < 4; ++k)
      wq[k] = *(const float4*)(w3 + (c << 4) + k * 4);  // uniform
#pragma unroll
    for (int t = 0; t < 5; ++t) {
      const float* rp = base + t * HDIM + (c << 4);
      float4 v0 = *(const float4*)(rp + 0);  // 2-addr ds_read broadcast
      float4 v1 = *(const float4*)(rp + 4);
      float4 v2 = *(const float4*)(rp + 8);
      float4 v3 = *(const float4*)(rp + 12);
      accA[t] = g4pk8(spA[0], spA[1], wq[0], wq[1], v0, v1, accA[t]);
      accA[t] = g4pk8(spA[2], spA[3], wq[2], wq[3], v2, v3, accA[t]);
      accB[t] = g4pk8(spB[0], spB[1], wq[0], wq[1], v0, v1, accB[t]);
      accB[t] = g4pk8(spB[2], spB[3], wq[2], wq[3], v2, v3, accB[t]);
    }
  }
}

// Fused per 40-target tile, 256 threads (R23-proven structure verbatim;
// only change: per-wave c-skew in phase 3).
// score[b][n] = C - 2 * sum_h w3[h] * rcp(fma(esp[b][h], etp[n][h], 1))
__global__ __launch_bounds__(256) void taa_fused(
    const float* __restrict__ emb, const float* __restrict__ W2,
    const float* __restrict__ b2, const float* __restrict__ esp4,
    const float* __restrict__ w3, const float* __restrict__ Cptr,
    float* __restrict__ out, int N) {
  __shared__ float sm[NT][132];       // emb tile, padded stride
  __shared__ float et[NT * HDIM];     // exp2(tp') tile
  const int nb = blockIdx.x * NT;

  // Phase 1: stage emb tile (coalesced float4, 5 per thread).
  for (int k = threadIdx.x; k < NT * 32; k += 256) {
    int r = k >> 5, c4 = k & 31;
    float4 v = make_float4(0.f, 0.f, 0.f, 0.f);
    if (nb + r < N) v = ((const float4*)(emb + (size_t)(nb + r) * EDIM))[c4];
    *(float4*)&sm[r][c4 * 4] = v;
  }
  __syncthreads();

  // Phase 2: GEMM + exp2 -> et (LDS). Thread = 5 rows x 4 h (R23 verbatim).
  {
    const int h4 = (threadIdx.x & 31) * 4;
    const int rg = threadIdx.x >> 5;  // 8 groups of 5 rows
    float acc[5][4];
#pragma unroll
    for (int j = 0; j < 5; ++j)
#pragma unroll
      for (int q = 0; q < 4; ++q) acc[j][q] = 0.f;
    for (int e = 0; e < EDIM; e += 4) {
      float4 w[4];
#pragma unroll
      for (int q = 0; q < 4; ++q)
        w[q] = *(const float4*)(W2 + (size_t)(e + q) * HDIM + h4);
#pragma unroll
      for (int j = 0; j < 5; ++j) {
        float4 em = *(const float4*)&sm[rg * 5 + j][e];
        acc[j][0] = fmaf(em.x, w[0].x, acc[j][0]);
        acc[j][1] = fmaf(em.x, w[0].y, acc[j][1]);
        acc[j][2] = fmaf(em.x, w[0].z, acc[j][2]);
        acc[j][3] = fmaf(em.x, w[0].w, acc[j][3]);
        acc[j][0] = fmaf(em.y, w[1].x, acc[j][0]);
        acc[j][1] = fmaf(em.y, w[1].y, acc[j][1]);
        acc[j][2] = fmaf(em.y, w[1].z, acc[j][2]);
        acc[j][3] = fmaf(em.y, w[1].w, acc[j][3]);
        acc[j][0] = fmaf(em.z, w[2].x, acc[j][0]);
        acc[j][1] = fmaf(em.z, w[2].y, acc[j][1]);
        acc[j][2] = fmaf(em.z, w[2].z, acc[j][2]);
        acc[j][3] = fmaf(em.z, w[2].w, acc[j][3]);
        acc[j][0] = fmaf(em.w, w[3].x, acc[j][0]);
        acc[j][1] = fmaf(em.w, w[3].y, acc[j][1]);
        acc[j][2] = fmaf(em.w, w[3].z, acc[j][2]);
        acc[j][3] = fmaf(em.w, w[3].w, acc[j][3]);
      }
    }
    float4 bb2 = *(const float4*)(b2 + h4);
#pragma unroll
    for (int j = 0; j < 5; ++j) {
      int nr = rg * 5 + j;
      float4 o;
      o.x = fexp2((acc[j][0] + bb2.x) * KSCALE);
      o.y = fexp2((acc[j][1] + bb2.y) * KSCALE);
      o.z = fexp2((acc[j][2] + bb2.z) * KSCALE);
      o.w = fexp2((acc[j][3] + bb2.w) * KSCALE);
      *(float4*)&et[nr * HDIM + h4] = o;  // wave-contiguous, conflict-free
    }
  }
  __syncthreads();

  // Phase 3: scoring with per-wave c-skew. lane&31 = session-pair;
  // (wv*2 + lane>>5) -> 5-target group. Thread = 2 sessions x 5 targets.
  const int lane = threadIdx.x & 63;
  const int wv = threadIdx.x >> 6;  // 0..3
  const int sp2 = lane & 31;        // sessions 2*sp2, 2*sp2+1
  const int th = lane >> 5;
  const int t0 = (wv * 2 + th) * 5; // 0,5,...,35
  float accA[5] = {0.f, 0.f, 0.f, 0.f, 0.f};
  float accB[5] = {0.f, 0.f, 0.f, 0.f, 0.f};
  score5x2(et, t0, sp2, esp4, w3, accA, accB, wv * 2);

  const float Cv = *Cptr;  // uniform
  const int n0 = nb + t0;
  const int sA = sp2 * 2, sB = sA + 1;
  float* poA = out + (size_t)sA * N + n0;
  float* poB = out + (size_t)sB * N + n0;
#pragma unroll
  for (int t = 0; t < 5; ++t) {
    if (n0 + t < N) {
      poA[t] = fmaf(-2.f, accA[t], Cv);
      poB[t] = fmaf(-2.f, accB[t], Cv);
    }
  }
}

extern "C" void kernel_launch(void* const* d_in, const int* in_sizes, int n_in,
                              void* d_out, int out_size, void* d_ws, size_t ws_size,
                              hipStream_t stream) {
  const float* sess = (const float*)d_in[0];
  const float* emb  = (const float*)d_in[1];
  const float* W1   = (const float*)d_in[2];
  const float* b1   = (const float*)d_in[3];
  const float* W2   = (const float*)d_in[4];
  const float* b2   = (const float*)d_in[5];
  const float* W3   = (const float*)d_in[6];
  const float* b3   = (const float*)d_in[7];
  float* out = (float*)d_out;
  const int B = in_sizes[0] / EDIM;   // 64
  const int N = in_sizes[1] / EDIM;   // 20000

  float* esp4 = (float*)d_ws;                     // B*128 floats (packed)
  float* Cp   = esp4 + (size_t)BSES * HDIM;       // 1 float

  taa_esp<<<(B * HDIM + 255) / 256, 256, 0, stream>>>(sess, W1, b1, W3, b3,
                                                      esp4, Cp);
  taa_fused<<<(N + NT - 1) / NT, 256, 0, stream>>>(emb, W2, b2, esp4, W3, Cp,
                                                   out, N);
}

// Round 26
// 32.228 us; speedup vs baseline: 1.4829x; 1.2229x over previous
//
#include <hip/hip_runtime.h>

#define BSES 64
#define EDIM 128
#define HDIM 128
#define NT 40   // targets per block: 500 blocks = 1.95/CU (balanced grid)
#define ETS 132 // et row stride (floats)
#define KSCALE 2.8853900817779268f  // 2*log2(e): exp(2x) = exp2(KSCALE*x)

typedef float v2f __attribute__((ext_vector_type(2)));
typedef __attribute__((ext_vector_type(8))) short short8;
typedef __attribute__((ext_vector_type(4))) float f32x4;

__device__ __forceinline__ float fexp2(float x) {
#if __has_builtin(__builtin_amdgcn_exp2f)
  return __builtin_amdgcn_exp2f(x);
#else
  return exp2f(x);
#endif
}
__device__ __forceinline__ float frcp(float x) {
#if __has_builtin(__builtin_amdgcn_rcpf)
  return __builtin_amdgcn_rcpf(x);
#else
  return 1.0f / x;
#endif
}
__device__ __forceinline__ v2f mkv2(float a, float b) {
  v2f r;
  r.x = a;
  r.y = b;
  return r;
}
// fp32 -> bf16 round-to-nearest-even (finite inputs).
__device__ __forceinline__ unsigned short f2bf(float f) {
  unsigned int u = __float_as_uint(f);
  return (unsigned short)((u + 0x7FFFu + ((u >> 16) & 1u)) >> 16);
}

// 8-term batched reciprocal sum via PACKED f32 (R20/R22/R23-proven).
__device__ __forceinline__ float g4pk8(float4 s0, float4 s1, float4 w0,
                                       float4 w1, float4 v0, float4 v1,
                                       float acc) {
  const v2f one = {1.f, 1.f};
  v2f s01 = mkv2(s0.x, s0.y), s23 = mkv2(s0.z, s0.w);
  v2f s45 = mkv2(s1.x, s1.y), s67 = mkv2(s1.z, s1.w);
  v2f w01 = mkv2(w0.x, w0.y), w23 = mkv2(w0.z, w0.w);
  v2f w45 = mkv2(w1.x, w1.y), w67 = mkv2(w1.z, w1.w);
  v2f v01 = mkv2(v0.x, v0.y), v23 = mkv2(v0.z, v0.w);
  v2f v45 = mkv2(v1.x, v1.y), v67 = mkv2(v1.z, v1.w);
  v2f x01 = __builtin_elementwise_fma(s01, v01, one);
  v2f x23 = __builtin_elementwise_fma(s23, v23, one);
  v2f x45 = __builtin_elementwise_fma(s45, v45, one);
  v2f x67 = __builtin_elementwise_fma(s67, v67, one);
  v2f p03 = x01 * x23;
  v2f p47 = x45 * x67;
  v2f n03 = __builtin_elementwise_fma(w23, x01, w01 * x23);
  v2f n47 = __builtin_elementwise_fma(w67, x45, w45 * x67);
  v2f num = __builtin_elementwise_fma(n47, p03, n03 * p47);
  v2f den = p03 * p47;
  acc = fmaf(num.x, frcp(den.x), acc);
  acc = fmaf(num.y, frcp(den.y), acc);
  return acc;
}

// Session projection (proven) + W2 bf16 B-fragment precompute.
// esp4 PACKED [h/4][b][4]; C = sum(W3)+b3; w2f[nt][ks][l][j] =
// bf16(W2[ks*32+(l>>4)*8+j][nt*16+(l&15)]) -- MFMA B-frag layout.
__global__ __launch_bounds__(256) void taa_esp(
    const float* __restrict__ sess, const float* __restrict__ W1,
    const float* __restrict__ b1, const float* __restrict__ W2,
    const float* __restrict__ W3, const float* __restrict__ b3,
    float* __restrict__ esp4, float* __restrict__ C_out,
    unsigned short* __restrict__ w2f) {
  int t = blockIdx.x * 256 + threadIdx.x;
  if (t < BSES * HDIM) {
    int b = t >> 7, h = t & 127;
    const float* srow = sess + b * EDIM;
    float acc = 0.f;
#pragma unroll 4
    for (int e = 0; e < EDIM; ++e)
      acc = fmaf(srow[e], W1[e * HDIM + h], acc);
    esp4[(h >> 2) * 256 + b * 4 + (h & 3)] = fexp2((acc + b1[h]) * KSCALE);
  }
  // W2 B-fragments: 16384 elements over 8192 threads (2 each).
#pragma unroll
  for (int rep = 0; rep < 2; ++rep) {
    int idx = t + rep * 8192;
    int j = idx & 7;
    int l = (idx >> 3) & 63;
    int ks = (idx >> 9) & 3;
    int nt = (idx >> 11) & 7;
    int k = ks * 32 + ((l >> 4) << 3) + j;
    int n = nt * 16 + (l & 15);
    w2f[idx] = f2bf(W2[k * HDIM + n]);
  }
  if (t == 0) {
    float s = b3[0];
    for (int i = 0; i < HDIM; ++i) s += W3[i];
    *C_out = s;
  }
}

// Score 5 targets x TWO sessions (R23-proven; et row stride ETS).
__device__ __forceinline__ void score5x2(
    const float* __restrict__ et, int t0, int sp2,
    const float* __restrict__ esp4, const float* __restrict__ w3,
    float accA[5], float accB[5]) {
  const float* base = et + t0 * ETS;
#pragma unroll 2
  for (int c = 0; c < 8; ++c) {
    float4 spA[4], spB[4];
#pragma unroll
    for (int k = 0; k < 4; ++k) {
      const float* p = esp4 + ((c << 2) + k) * 256 + (sp2 << 3);
      spA[k] = *(const float4*)p;        // session 2*sp2
      spB[k] = *(const float4*)(p + 4);  // session 2*sp2+1
    }
    float4 wq[4];
#pragma unroll
    for (int k = 0; k < 4; ++k)
      wq[k] = *(const float4*)(w3 + (c << 4) + k * 4);  // uniform
#pragma unroll
    for (int t = 0; t < 5; ++t) {
      const float* rp = base + t * ETS + (c << 4);
      float4 v0 = *(const float4*)(rp + 0);  // 2-addr ds_read broadcast
      float4 v1 = *(const float4*)(rp + 4);
      float4 v2 = *(const float4*)(rp + 8);
      float4 v3 = *(const float4*)(rp + 12);
      accA[t] = g4pk8(spA[0], spA[1], wq[0], wq[1], v0, v1, accA[t]);
      accA[t] = g4pk8(spA[2], spA[3], wq[2], wq[3], v2, v3, accA[t]);
      accB[t] = g4pk8(spB[0], spB[1], wq[0], wq[1], v0, v1, accB[t]);
      accB[t] = g4pk8(spB[2], spB[3], wq[2], wq[3], v2, v3, accB[t]);
    }
  }
}

// Fused per 40-target tile, 256 threads. P2 now on MATRIX CORES:
// emb rows -> bf16 A-frags in LDS (frag-major, lane-linear, conflict-free);
// W2 B-frags from global (L2-hot 32KB, coalesced); 24x mfma_16x16x32_bf16
// per wave (M padded 40->48, pad rows discarded). A/B use the SAME
// k-packing rule so any internal k-permutation cancels; C/D mapping is the
// m89-verified col=lane&15, row=(lane>>4)*4+reg. P3 = R23-proven scoring.
// score[b][n] = C - 2 * sum_h w3[h] * rcp(fma(esp[b][h], etp[n][h], 1))
__global__ __launch_bounds__(256) void taa_fused(
    const float* __restrict__ emb, const unsigned short* __restrict__ w2f,
    const float* __restrict__ b2, const float* __restrict__ esp4,
    const float* __restrict__ w3, const float* __restrict__ Cptr,
    float* __restrict__ out, int N) {
  __shared__ short ebf[12 * 512];   // A-frags: [mt*4+ks][lane][8], 12 KB
  __shared__ float et[NT * ETS];    // exp2(tp') tile, 21.1 KB
  const int tid = threadIdx.x;
  const int l = tid & 63;
  const int wv = tid >> 6;  // 0..3
  const int nb = blockIdx.x * NT;

  // Phase 1: convert emb rows -> bf16 A-fragments in LDS.
  // Plane p=(mt,ks): lane l holds row mt*16+(l&15), k = ks*32+(l>>4)*8+[0,8).
#pragma unroll
  for (int pi = 0; pi < 3; ++pi) {
    const int p = wv + pi * 4;  // 0..11
    const int mt = p >> 2, ks = p & 3;
    int row = nb + mt * 16 + (l & 15);
    row = min(row, N - 1);  // pad rows: valid load, result discarded
    const int k0 = ks * 32 + ((l >> 4) << 3);
    const float4 f0 = *(const float4*)(emb + (size_t)row * EDIM + k0);
    const float4 f1 = *(const float4*)(emb + (size_t)row * EDIM + k0 + 4);
    short8 v;
    v[0] = (short)f2bf(f0.x);
    v[1] = (short)f2bf(f0.y);
    v[2] = (short)f2bf(f0.z);
    v[3] = (short)f2bf(f0.w);
    v[4] = (short)f2bf(f1.x);
    v[5] = (short)f2bf(f1.y);
    v[6] = (short)f2bf(f1.z);
    v[7] = (short)f2bf(f1.w);
    *(short8*)&ebf[(p << 9) + (l << 3)] = v;  // lane-linear b128 write
  }
  __syncthreads();

  // Phase 2: MFMA GEMM. Wave wv owns n-tiles {2wv, 2wv+1} x 3 m-tiles.
  {
    const int nt0 = wv * 2;
    f32x4 acc[3][2];
#pragma unroll
    for (int mt = 0; mt < 3; ++mt)
#pragma unroll
      for (int j = 0; j < 2; ++j) acc[mt][j] = (f32x4){0.f, 0.f, 0.f, 0.f};
#pragma unroll
    for (int ks = 0; ks < 4; ++ks) {
      short8 a0 = *(short8*)&ebf[((0 * 4 + ks) << 9) + (l << 3)];
      short8 a1 = *(short8*)&ebf[((1 * 4 + ks) << 9) + (l << 3)];
      short8 a2 = *(short8*)&ebf[((2 * 4 + ks) << 9) + (l << 3)];
      short8 b0 = *(const short8*)(w2f + (((nt0 + 0) * 4 + ks) << 9) + (l << 3));
      short8 b1 = *(const short8*)(w2f + (((nt0 + 1) * 4 + ks) << 9) + (l << 3));
      acc[0][0] = __builtin_amdgcn_mfma_f32_16x16x32_bf16(a0, b0, acc[0][0], 0, 0, 0);
      acc[0][1] = __builtin_amdgcn_mfma_f32_16x16x32_bf16(a0, b1, acc[0][1], 0, 0, 0);
      acc[1][0] = __builtin_amdgcn_mfma_f32_16x16x32_bf16(a1, b0, acc[1][0], 0, 0, 0);
      acc[1][1] = __builtin_amdgcn_mfma_f32_16x16x32_bf16(a1, b1, acc[1][1], 0, 0, 0);
      acc[2][0] = __builtin_amdgcn_mfma_f32_16x16x32_bf16(a2, b0, acc[2][0], 0, 0, 0);
      acc[2][1] = __builtin_amdgcn_mfma_f32_16x16x32_bf16(a2, b1, acc[2][1], 0, 0, 0);
    }
    // Epilogue: C/D lane map col=lane&15, row=(lane>>4)*4+reg (m89).
    const int nA = nt0 * 16 + (l & 15);
    const int nB = nA + 16;
    const float b2A = b2[nA], b2B = b2[nB];
#pragma unroll
    for (int mt = 0; mt < 3; ++mt) {
#pragma unroll
      for (int r = 0; r < 4; ++r) {
        const int m = mt * 16 + ((l >> 4) << 2) + r;
        if (m < NT) {
          et[m * ETS + nA] = fexp2((acc[mt][0][r] + b2A) * KSCALE);
          et[m * ETS + nB] = fexp2((acc[mt][1][r] + b2B) * KSCALE);
        }
      }
    }
  }
  __syncthreads();

  // Phase 3: scoring (R23-proven). lane&31 = session-pair;
  // (wv*2 + lane>>5) -> 5-target group. Thread = 2 sessions x 5 targets.
  const int sp2 = l & 31;          // sessions 2*sp2, 2*sp2+1
  const int th = l >> 5;
  const int t0 = (wv * 2 + th) * 5;  // 0,5,...,35
  float accA[5] = {0.f, 0.f, 0.f, 0.f, 0.f};
  float accB[5] = {0.f, 0.f, 0.f, 0.f, 0.f};
  score5x2(et, t0, sp2, esp4, w3, accA, accB);

  const float Cv = *Cptr;  // uniform
  const int n0 = nb + t0;
  const int sA = sp2 * 2, sB = sA + 1;
  float* poA = out + (size_t)sA * N + n0;
  float* poB = out + (size_t)sB * N + n0;
#pragma unroll
  for (int t = 0; t < 5; ++t) {
    if (n0 + t < N) {
      poA[t] = fmaf(-2.f, accA[t], Cv);
      poB[t] = fmaf(-2.f, accB[t], Cv);
    }
  }
}

extern "C" void kernel_launch(void* const* d_in, const int* in_sizes, int n_in,
                              void* d_out, int out_size, void* d_ws, size_t ws_size,
                              hipStream_t stream) {
  const float* sess = (const float*)d_in[0];
  const float* emb  = (const float*)d_in[1];
  const float* W1   = (const float*)d_in[2];
  const float* b1   = (const float*)d_in[3];
  const float* W2   = (const float*)d_in[4];
  const float* b2   = (const float*)d_in[5];
  const float* W3   = (const float*)d_in[6];
  const float* b3   = (const float*)d_in[7];
  float* out = (float*)d_out;
  const int B = in_sizes[0] / EDIM;   // 64
  const int N = in_sizes[1] / EDIM;   // 20000

  float* esp4 = (float*)d_ws;                       // 8192 floats (packed)
  float* Cp   = esp4 + (size_t)BSES * HDIM;         // 1 float
  unsigned short* w2f = (unsigned short*)(Cp + 4);  // 16384 bf16 (16B-aligned)

  taa_esp<<<(B * HDIM + 255) / 256, 256, 0, stream>>>(sess, W1, b1, W2, W3,
                                                      b3, esp4, Cp, w2f);
  taa_fused<<<(N + NT - 1) / NT, 256, 0, stream>>>(emb, w2f, b2, esp4, W3,
                                                   Cp, out, N);
}